// Round 11
// baseline (319.264 us; speedup 1.0000x reference)
//
#include <hip/hip_runtime.h>
#include <hip/hip_bf16.h>
#include <cmath>

#define E_ 256
#define H_ 8
#define DH 32
#define MLPD 1024
#define LATD 128
#define TOPK_ 32
#define BB 2
#define RR 1024
#define CC 4
#define NT 8192      // B*R*C tokens
#define BF 8         // B*C
#define SPLIT 768

using bf16x8 = __attribute__((ext_vector_type(8))) short;
using f32x4v = __attribute__((ext_vector_type(4))) float;

__device__ __forceinline__ unsigned short f2b(float x) {
    __hip_bfloat16 h = __float2bfloat16(x);
    return *reinterpret_cast<unsigned short*>(&h);
}
__device__ __forceinline__ float b2f(unsigned short u) {
    return __uint_as_float(((unsigned)u) << 16);
}

// ---------------------------------------------------------------------------
// Fused f32 -> bf16 converter (8 segments)
// ---------------------------------------------------------------------------
struct ConvArgs {
    const float* s[8];
    unsigned short* d[8];
    int cum[8];
};
__global__ __launch_bounds__(256) void convert_f2b(ConvArgs a, int totq)
{
    int q = blockIdx.x * 256 + threadIdx.x;
    if (q >= totq) return;
    int seg = 0;
    while (q >= a.cum[seg]) seg++;
    int lq = q - (seg ? a.cum[seg - 1] : 0);
    float4 v = ((const float4*)a.s[seg])[lq];
    ushort4 o;
    o.x = f2b(v.x); o.y = f2b(v.y); o.z = f2b(v.z); o.w = f2b(v.w);
    ((ushort4*)a.d[seg])[lq] = o;
}

// ---------------------------------------------------------------------------
// Absorbed MLA weights:
//   W2[hl][e] = sum_d muw[(h*32+d)][l] * mqw[(h*32+d)][e]        (K-half)
//   W3[e][hl] = sum_d mow[e][h*32+d]   * muw[256+h*32+d][l]      (V-half)
// ---------------------------------------------------------------------------
__global__ __launch_bounds__(256) void make_w2w3(const float* __restrict__ mqw,
                                                 const float* __restrict__ muw,
                                                 const float* __restrict__ mow,
                                                 unsigned short* __restrict__ W2,
                                                 unsigned short* __restrict__ W3)
{
    int b = blockIdx.x, t = threadIdx.x;
    if (b < 1024) {
        int h = b >> 7, l = b & 127;
        float s2 = 0;
#pragma unroll 8
        for (int d = 0; d < 32; d++)
            s2 += muw[(size_t)(h * 32 + d) * 128 + l] * mqw[(size_t)(h * 32 + d) * 256 + t];
        W2[(size_t)b * 256 + t] = f2b(s2);
    } else {
        int e = b - 1024;
        for (int tt = t; tt < 1024; tt += 256) {
            int h = tt >> 7, l = tt & 127;
            float s3 = 0;
#pragma unroll 8
            for (int d = 0; d < 32; d++)
                s3 += muw[(size_t)(256 + h * 32 + d) * 128 + l] * mow[(size_t)e * 256 + h * 32 + d];
            W3[(size_t)e * 1024 + tt] = f2b(s3);
        }
    }
}

// ---------------------------------------------------------------------------
// bf16 MFMA GEMM: C[M][N] = A(MxK bf16) @ W(NxK bf16)^T (+bias)(+gelu)(+res f32)
// ---------------------------------------------------------------------------
template<int TM, int TN, int BIAS, int GELU, int RES, int AMAP, int OMAP, int OUTBF>
__global__ __launch_bounds__(256) void gemm_mfma(
    const unsigned short* __restrict__ A, const unsigned short* __restrict__ W,
    const float* __restrict__ bias, const float* __restrict__ res,
    float* __restrict__ Cf, unsigned short* __restrict__ Ch,
    int M, int N, int K)
{
    __shared__ __align__(16) unsigned short As[TM * 40];
    __shared__ __align__(16) unsigned short Bs[TN * 40];
    const int tid = threadIdx.x;
    const int lane = tid & 63, wave = tid >> 6;
    const int wr = wave >> 1, wc = wave & 1;
    const int m0 = blockIdx.y * TM, n0 = blockIdx.x * TN;

    int ra, kqa;
    if constexpr (TM == 128) { ra = tid >> 1; kqa = (tid & 1) * 16; }
    else                     { ra = tid >> 2; kqa = (tid & 3) * 8; }
    int rb, kqb;
    if constexpr (TN == 128) { rb = tid >> 1; kqb = (tid & 1) * 16; }
    else                     { rb = tid >> 2; kqb = (tid & 3) * 8; }

    int am = m0 + ra;
    size_t arow = AMAP ? ((size_t)(am / SPLIT) * RR + (am % SPLIT)) : (size_t)am;
    const unsigned short* Ap = A + arow * (size_t)K + kqa;
    const unsigned short* Bp = W + (size_t)(n0 + rb) * K + kqb;

    constexpr int FM = TM / 32, FN = TN / 32;
    f32x4v acc[FM][FN];
#pragma unroll
    for (int i = 0; i < FM; i++)
#pragma unroll
        for (int j = 0; j < FN; j++) acc[i][j] = (f32x4v){0.f, 0.f, 0.f, 0.f};

    const int kof = (lane >> 4) * 8;
    int arow_lds[FM], brow_lds[FN];
#pragma unroll
    for (int f = 0; f < FM; f++)
        arow_lds[f] = (wr * (TM / 2) + f * 16 + (lane & 15)) * 40 + kof;
#pragma unroll
    for (int f = 0; f < FN; f++)
        brow_lds[f] = (wc * (TN / 2) + f * 16 + (lane & 15)) * 40 + kof;

    for (int k0 = 0; k0 < K; k0 += 32) {
        int4 va0, va1, vb0, vb1;
        va0 = *(const int4*)(Ap + k0);
        if constexpr (TM == 128) va1 = *(const int4*)(Ap + k0 + 8);
        vb0 = *(const int4*)(Bp + k0);
        if constexpr (TN == 128) vb1 = *(const int4*)(Bp + k0 + 8);
        __syncthreads();
        *(int4*)&As[ra * 40 + kqa] = va0;
        if constexpr (TM == 128) *(int4*)&As[ra * 40 + kqa + 8] = va1;
        *(int4*)&Bs[rb * 40 + kqb] = vb0;
        if constexpr (TN == 128) *(int4*)&Bs[rb * 40 + kqb + 8] = vb1;
        __syncthreads();
        bf16x8 af[FM], bfr[FN];
#pragma unroll
        for (int f = 0; f < FM; f++) af[f] = *(const bf16x8*)&As[arow_lds[f]];
#pragma unroll
        for (int f = 0; f < FN; f++) bfr[f] = *(const bf16x8*)&Bs[brow_lds[f]];
#pragma unroll
        for (int fm = 0; fm < FM; fm++)
#pragma unroll
            for (int fn = 0; fn < FN; fn++)
                acc[fm][fn] = __builtin_amdgcn_mfma_f32_16x16x32_bf16(
                    af[fm], bfr[fn], acc[fm][fn], 0, 0, 0);
    }

#pragma unroll
    for (int fm = 0; fm < FM; fm++) {
#pragma unroll
        for (int r = 0; r < 4; r++) {
            int row = m0 + wr * (TM / 2) + fm * 16 + ((lane >> 4) << 2) + r;
            size_t orow;
            if (OMAP) {
                int bc = row >> 10, rr = row & 1023;
                int b = bc >> 2, c = bc & 3;
                orow = ((size_t)(b * RR + rr)) * CC + c;
            } else orow = (size_t)row;
#pragma unroll
            for (int fn = 0; fn < FN; fn++) {
                int col = n0 + wc * (TN / 2) + fn * 16 + (lane & 15);
                float v = acc[fm][fn][r];
                if (BIAS) v += bias[col];
                if (GELU) v = 0.5f * v * (1.0f + erff(v * 0.70710678118654752f));
                if (RES)  v += res[(size_t)row * N + col];
                if (OUTBF) Ch[orow * (size_t)N + col] = f2b(v);
                else       Cf[orow * (size_t)N + col] = v;
            }
        }
    }
}

// ---------------------------------------------------------------------------
// Feature attention: seq len 4, per (b,r) block. Reads bf16 qkv.
// ---------------------------------------------------------------------------
__global__ __launch_bounds__(256) void fa_attn(const unsigned short* __restrict__ qkv16,
                                               unsigned short* __restrict__ outb)
{
    int seq = blockIdx.x, tid = threadIdx.x;
    __shared__ float sq[4][E_], sk[4][E_], sv[4][E_];
    __shared__ float ss[H_][4][4];
    __shared__ float sw[H_][4][4];
    const uint4* base = (const uint4*)(qkv16 + (size_t)seq * 3072);
#pragma unroll
    for (int p = 0; p < 2; p++) {
        int pos = tid + p * 256;           // 0..383 uint4 units (8 bf16 each)
        if (pos < 384) {
            uint4 v = base[pos];
            unsigned short u[8];
            *(uint4*)u = v;
            int flat = pos * 8;
            int i = flat / 768, c = flat % 768;
            float* dst = (c < 256) ? &sq[i][c] : (c < 512) ? &sk[i][c - 256] : &sv[i][c - 512];
#pragma unroll
            for (int t = 0; t < 8; t++) dst[t] = b2f(u[t]);
        }
    }
    __syncthreads();
    if (tid < 128) {
        int h = tid >> 4, i = (tid >> 2) & 3, j = tid & 3;
        float s = 0;
        for (int d = 0; d < DH; d++) s += sq[i][h * DH + d] * sk[j][h * DH + d];
        ss[h][i][j] = s * 0.17677669529663688f;   // 1/sqrt(32)
    }
    __syncthreads();
    if (tid < 32) {
        int h = tid >> 2, i = tid & 3;
        float m = ss[h][i][0];
        for (int j = 1; j < 4; j++) m = fmaxf(m, ss[h][i][j]);
        float e[4], sum = 0;
        for (int j = 0; j < 4; j++) { e[j] = expf(ss[h][i][j] - m); sum += e[j]; }
        float inv = 1.0f / sum;
        for (int j = 0; j < 4; j++) sw[h][i][j] = e[j] * inv;
    }
    __syncthreads();
    int e = tid, h = e >> 5;
    for (int i = 0; i < 4; i++) {
        float o = 0;
        for (int j = 0; j < 4; j++) o += sw[h][i][j] * sv[j][e];
        outb[((size_t)(seq * 4 + i)) * E_ + e] = f2b(o);
    }
}

// ---------------------------------------------------------------------------
// LayerNorm: 4 rows per block (one row per wave). OMAP=1: token -> st row.
// ---------------------------------------------------------------------------
template<int OMAP, int WB>
__global__ __launch_bounds__(256) void ln_k(const float* __restrict__ in,
                                            const float* __restrict__ g,
                                            const float* __restrict__ bta,
                                            float* __restrict__ out,
                                            unsigned short* __restrict__ outh)
{
    int row = blockIdx.x * 4 + (threadIdx.x >> 6);
    int t = threadIdx.x & 63;
    float4 v = ((const float4*)(in + (size_t)row * E_))[t];
    float s = v.x + v.y + v.z + v.w;
#pragma unroll
    for (int o = 32; o >= 1; o >>= 1) s += __shfl_xor(s, o);
    float mean = s * (1.0f / E_);
    float dx0 = v.x - mean, dx1 = v.y - mean, dx2 = v.z - mean, dx3 = v.w - mean;
    float q = dx0 * dx0 + dx1 * dx1 + dx2 * dx2 + dx3 * dx3;
#pragma unroll
    for (int o = 32; o >= 1; o >>= 1) q += __shfl_xor(q, o);
    float inv = rsqrtf(q * (1.0f / E_) + 1e-5f);
    size_t orow;
    if (OMAP == 1) {
        int b = row >> 12, r = (row >> 2) & 1023, c = row & 3;
        orow = ((size_t)(b * CC + c)) * RR + r;
    } else orow = (size_t)row;
    int c0 = t * 4;
    float4 o;
    o.x = dx0 * inv * g[c0 + 0] + bta[c0 + 0];
    o.y = dx1 * inv * g[c0 + 1] + bta[c0 + 1];
    o.z = dx2 * inv * g[c0 + 2] + bta[c0 + 2];
    o.w = dx3 * inv * g[c0 + 3] + bta[c0 + 3];
    ((float4*)(out + orow * E_))[t] = o;
    if (WB) {
        ushort4 oh; oh.x = f2b(o.x); oh.y = f2b(o.y); oh.z = f2b(o.z); oh.w = f2b(o.w);
        ((ushort4*)(outh + orow * E_))[t] = oh;
    }
}

// ---------------------------------------------------------------------------
// Indexer scales + k-quantize fused.
// ---------------------------------------------------------------------------
__global__ __launch_bounds__(256) void idx_scales_quant(const float* __restrict__ qk32,
                                                        float* __restrict__ scl,
                                                        signed char* __restrict__ ki8)
{
    int id = blockIdx.x;
    int type = id / 32, bf = (id % 32) >> 2, h = id & 3;
    int cofs = (type == 2) ? 32 : 0;
    int r0 = (type == 1) ? SPLIT : 0;
    int r1 = (type == 1) ? RR : SPLIT;
    float m = 0;
    for (int r = r0 + (int)threadIdx.x; r < r1; r += 256) {
        const float* p = qk32 + ((size_t)(bf * RR + r)) * 64 + cofs + h * 8;
        for (int dd = 0; dd < 8; dd++) m = fmaxf(m, fabsf(p[dd]));
    }
#pragma unroll
    for (int o = 32; o >= 1; o >>= 1) m = fmaxf(m, __shfl_xor(m, o));
    __shared__ float red[4];
    __shared__ float sscl;
    if ((threadIdx.x & 63) == 0) red[threadIdx.x >> 6] = m;
    __syncthreads();
    if (threadIdx.x == 0) {
        m = fmaxf(fmaxf(red[0], red[1]), fmaxf(red[2], red[3]));
        float sc = (m + 1e-6f) / 127.0f;
        scl[id] = sc;
        sscl = sc;
    }
    __syncthreads();
    if (type == 2) {
        float ks = sscl;
        for (int r = threadIdx.x; r < SPLIT; r += 256) {
            const float* p = qk32 + ((size_t)(bf * RR + r)) * 64 + 32 + h * 8;
            signed char* o = ki8 + ((size_t)(bf * SPLIT + r)) * 32 + h * 8;
#pragma unroll
            for (int dd = 0; dd < 8; dd++)
                o[dd] = (signed char)fminf(fmaxf(rintf(p[dd] / ks), -127.f), 127.f);
        }
    }
}

// ---------------------------------------------------------------------------
// Indexer scores + top-32 via EXACT radix-select (jax.lax.top_k tie rule).
// ---------------------------------------------------------------------------
__global__ __launch_bounds__(256) void idx_score_topk(const float* __restrict__ qk32,
                                                      const signed char* __restrict__ ki8,
                                                      const float* __restrict__ scl,
                                                      const float* __restrict__ ow,
                                                      int* __restrict__ idx_out)
{
    int bid = blockIdx.x, tid = threadIdx.x;
    int bf = bid >> 10, qr = bid & 1023;
    int sel = (qr < SPLIT) ? 0 : 32;
    __shared__ float qi[32];
    __shared__ float fac[4];
    __shared__ unsigned keyhi[SPLIT];
    __shared__ __align__(16) unsigned long long cand[SPLIT];
    __shared__ int hist[256], hist2[256], Sarr[256];
    __shared__ int bsel1, bsel2, ccnt;

    hist[tid] = 0; hist2[tid] = 0;
    if (tid == 0) ccnt = 0;
    if (tid < 32) {
        int h = tid >> 3;
        float qs = scl[sel + bf * 4 + h];
        float v = qk32[(size_t)bid * 64 + tid];
        qi[tid] = fminf(fmaxf(rintf(v / qs), -127.f), 127.f);
    }
    if (tid < 4) {
        float qs = scl[sel + bf * 4 + tid];
        float ks = scl[64 + bf * 4 + tid];
        fac[tid] = __fmul_rn(qs, ks);
    }
    __syncthreads();
    float ow0 = ow[0], ow1 = ow[1], ow2 = ow[2], ow3 = ow[3];
    for (int k = tid; k < SPLIT; k += 256) {
        const int4* kp4 = (const int4*)(ki8 + ((size_t)(bf * SPLIT + k)) * 32);
        int4 w0 = kp4[0], w1 = kp4[1];
        int wd[8] = {w0.x, w0.y, w0.z, w0.w, w1.x, w1.y, w1.z, w1.w};
        float owv[4] = {ow0, ow1, ow2, ow3};
        float r = 0;
#pragma unroll
        for (int h = 0; h < 4; h++) {
            float dot = 0.f;
#pragma unroll
            for (int b = 0; b < 2; b++) {
                unsigned int w = (unsigned int)wd[h * 2 + b];
#pragma unroll
                for (int by = 0; by < 4; by++) {
                    float kv = (float)((signed char)(w >> (8 * by)));
                    dot = fmaf(qi[h * 8 + b * 4 + by], kv, dot);
                }
            }
            float sc = fmaxf(__fmul_rn(dot, fac[h]), 0.f);
            r = __fadd_rn(r, __fmul_rn(sc, owv[h]));
        }
        unsigned int bitsv = __float_as_uint(r);
        unsigned int mono = (bitsv & 0x80000000u) ? ~bitsv : (bitsv | 0x80000000u);
        if (mono == 0x7FFFFFFFu) mono = 0x80000000u;   // canonicalize -0 == +0
        keyhi[k] = mono;
        atomicAdd(&hist[mono >> 24], 1);
    }
    __syncthreads();
    if (tid < 64) {
        int4 h4 = *(const int4*)&hist[tid * 4];
        int local = h4.x + h4.y + h4.z + h4.w;
        int s = local;
#pragma unroll
        for (int o = 1; o < 64; o <<= 1) {
            int x = __shfl_down(s, o);
            if (tid + o < 64) s += x;
        }
        int sufE = s - local;
        Sarr[tid * 4 + 0] = sufE + h4.y + h4.z + h4.w;
        Sarr[tid * 4 + 1] = sufE + h4.z + h4.w;
        Sarr[tid * 4 + 2] = sufE + h4.w;
        Sarr[tid * 4 + 3] = sufE;
    }
    __syncthreads();
    if (Sarr[tid] < TOPK_ && Sarr[tid] + hist[tid] >= TOPK_) bsel1 = tid;
    __syncthreads();
    const int b1 = bsel1;
    const int S1 = Sarr[b1];
    for (int k = tid; k < SPLIT; k += 256) {
        unsigned mono = keyhi[k];
        if ((int)(mono >> 24) == b1) atomicAdd(&hist2[(mono >> 16) & 255], 1);
    }
    __syncthreads();
    if (tid < 64) {
        int4 h4 = *(const int4*)&hist2[tid * 4];
        int local = h4.x + h4.y + h4.z + h4.w;
        int s = local;
#pragma unroll
        for (int o = 1; o < 64; o <<= 1) {
            int x = __shfl_down(s, o);
            if (tid + o < 64) s += x;
        }
        int sufE = s - local;
        Sarr[tid * 4 + 0] = sufE + h4.y + h4.z + h4.w;
        Sarr[tid * 4 + 1] = sufE + h4.z + h4.w;
        Sarr[tid * 4 + 2] = sufE + h4.w;
        Sarr[tid * 4 + 3] = sufE;
    }
    __syncthreads();
    if (S1 + Sarr[tid] < TOPK_ && S1 + Sarr[tid] + hist2[tid] >= TOPK_) bsel2 = tid;
    __syncthreads();
    const int b2 = bsel2;
    for (int k = tid; k < SPLIT; k += 256) {
        unsigned mono = keyhi[k];
        int hi = mono >> 24, mid = (mono >> 16) & 255;
        if (hi > b1 || (hi == b1 && mid >= b2)) {
            int s = atomicAdd(&ccnt, 1);
            cand[s] = ((unsigned long long)mono << 10) | (unsigned)(1023 - k);
        }
    }
    __syncthreads();
    const int n = ccnt;
    for (int ci = tid; ci < n; ci += 256) {
        unsigned long long mine = cand[ci];
        int r = 0;
        for (int j = 0; j < n; j++) r += (cand[j] > mine);
        if (r < TOPK_)
            idx_out[(size_t)bid * TOPK_ + r] = 1023 - (int)(mine & 1023ull);
    }
}

// ---------------------------------------------------------------------------
// Fused sparse MLA attention: one wave per query, 4 queries per block.
// Barrier-free (each wave owns a disjoint LDS slice).
// ---------------------------------------------------------------------------
__global__ __launch_bounds__(256) void mla_attn(const unsigned short* __restrict__ G16,
                                                const unsigned short* __restrict__ cb16,
                                                const int* __restrict__ idxb,
                                                unsigned short* __restrict__ Mo16)
{
    const int w = threadIdx.x >> 6, l = threadIdx.x & 63;
    const int bid = blockIdx.x * 4 + w;
    const int bf = bid >> 10;
    __shared__ __align__(16) unsigned short ct[4][128][40];  // C^T per wave
    __shared__ __align__(16) unsigned short wT[4][16][40];   // w^T per wave
    __shared__ int sidx[4][32];
    if (l < 32) sidx[w][l] = idxb[(size_t)bid * 32 + l];

    const int n16 = l & 15, g = l >> 4;

    // ---- stage C^T (transpose write) ----
    {
        int j = l >> 1, c0 = (l & 1) * 64;
        const unsigned short* crow = cb16 + ((size_t)(bf * SPLIT + sidx[w][j])) * 128 + c0;
#pragma unroll
        for (int e = 0; e < 8; e++) {
            uint4 v = *(const uint4*)(crow + e * 8);
            unsigned short tmp[8];
            *(uint4*)tmp = v;
#pragma unroll
            for (int t = 0; t < 8; t++) ct[w][c0 + e * 8 + t][j] = tmp[t];
        }
    }

    // ---- scores: S^T = G @ C^T (global-direct fragments) ----
    const unsigned short* Ab = G16 + (size_t)bid * 1024 + (size_t)(l & 7) * 128 + g * 8;
    const int j0 = sidx[w][n16], j1 = sidx[w][16 + n16];
    const unsigned short* B0 = cb16 + ((size_t)(bf * SPLIT + j0)) * 128 + g * 8;
    const unsigned short* B1 = cb16 + ((size_t)(bf * SPLIT + j1)) * 128 + g * 8;
    f32x4v s0 = {0.f, 0.f, 0.f, 0.f}, s1 = {0.f, 0.f, 0.f, 0.f};
#pragma unroll
    for (int c = 0; c < 4; c++) {
        bf16x8 a  = *(const bf16x8*)(Ab + c * 32);
        bf16x8 b0 = *(const bf16x8*)(B0 + c * 32);
        bf16x8 b1 = *(const bf16x8*)(B1 + c * 32);
        s0 = __builtin_amdgcn_mfma_f32_16x16x32_bf16(a, b0, s0, 0, 0, 0);
        s1 = __builtin_amdgcn_mfma_f32_16x16x32_bf16(a, b1, s1, 0, 0, 0);
    }

    // ---- softmax over j (32 vals: 16 lanes x 2 regs), per h-row ----
    const float scale = 0.17677669529663688f;
#pragma unroll
    for (int r = 0; r < 4; r++) {
        float a0 = s0[r] * scale, a1 = s1[r] * scale;
        float mx = fmaxf(a0, a1);
#pragma unroll
        for (int o = 1; o < 16; o <<= 1) mx = fmaxf(mx, __shfl_xor(mx, o));
        float e0 = expf(a0 - mx), e1 = expf(a1 - mx);
        float sm = e0 + e1;
#pragma unroll
        for (int o = 1; o < 16; o <<= 1) sm += __shfl_xor(sm, o);
        float inv = 1.0f / sm;
        wT[w][g * 4 + r][n16]      = f2b(e0 * inv);
        wT[w][g * 4 + r][16 + n16] = f2b(e1 * inv);
    }

    // ---- PV: M = W^T @ C ----
    bf16x8 aw = *(const bf16x8*)&wT[w][n16][g * 8];
#pragma unroll
    for (int t = 0; t < 8; t++) {
        bf16x8 bc = *(const bf16x8*)&ct[w][t * 16 + n16][g * 8];
        f32x4v m = {0.f, 0.f, 0.f, 0.f};
        m = __builtin_amdgcn_mfma_f32_16x16x32_bf16(aw, bc, m, 0, 0, 0);
        if (g < 2) {
#pragma unroll
            for (int r = 0; r < 4; r++)
                Mo16[(size_t)bid * 1024 + (size_t)(g * 4 + r) * 128 + t * 16 + n16] = f2b(m[r]);
        }
    }
}

// ---------------------------------------------------------------------------
extern "C" void kernel_launch(void* const* d_in, const int* in_sizes, int n_in,
                              void* d_out, int out_size, void* d_ws, size_t ws_size,
                              hipStream_t stream)
{
    (void)in_sizes; (void)n_in; (void)out_size; (void)ws_size;
    const float* src      = (const float*)d_in[0];
    const float* fa_in_w  = (const float*)d_in[2];
    const float* fa_in_b  = (const float*)d_in[3];
    const float* fa_out_w = (const float*)d_in[4];
    const float* fa_out_b = (const float*)d_in[5];
    const float* n1g = (const float*)d_in[6];
    const float* n1b = (const float*)d_in[7];
    const float* iqw = (const float*)d_in[8];
    const float* ikw = (const float*)d_in[9];
    const float* iow = (const float*)d_in[10];
    const float* mqw = (const float*)d_in[11];
    const float* mdw = (const float*)d_in[12];
    const float* muw = (const float*)d_in[13];
    const float* mow = (const float*)d_in[14];
    const float* n2g = (const float*)d_in[15];
    const float* n2b = (const float*)d_in[16];
    const float* l1w = (const float*)d_in[17];
    const float* l1b = (const float*)d_in[18];
    const float* l2w = (const float*)d_in[19];
    const float* l2b = (const float*)d_in[20];
    const float* n3g = (const float*)d_in[21];
    const float* n3b = (const float*)d_in[22];

    float* ws = (float*)d_ws;
    size_t off = 0;
    auto alloc = [&](size_t n) { float* p = ws + off; off += (n + 3) & ~(size_t)3; return p; };

    float* bigA = alloc((size_t)NT * 1024);   // qkv16 -> G16 -> x2
    float* Mh   = alloc((size_t)NT * 1024);   // Mo16; later h1 bf16
    float* tbuf = alloc((size_t)NT * E_);     // pre-LN buffer
    float* stb  = alloc((size_t)NT * E_);     // st f32 (post-LN1, transposed)
    float* cbws = alloc((size_t)BF * SPLIT * LATD / 2 + 16);   // cb16 bf16
    unsigned short* actBF1 = (unsigned short*)alloc((size_t)NT * E_ / 2);
    unsigned short* actBF2 = (unsigned short*)alloc((size_t)NT * E_ / 2);
    float* qk32 = alloc((size_t)NT * 64);
    float* scl = alloc(128);
    int*   idxb = (int*)alloc((size_t)NT * 32);
    signed char* ki8 = (signed char*)alloc((size_t)NT * 32 / 4);
    // FIX(R10): w16 holds 819200 bf16 (was sized 790528 -> l2w16 tail clobbered
    // wqk16, corrupting indexer weights). Size = sum of the 6 segments below.
    unsigned short* w16 = (unsigned short*)alloc(819200 / 2 + 16);
    unsigned short* wqk16 = (unsigned short*)alloc(16384 / 2 + 8);
    unsigned short* W2_16 = (unsigned short*)alloc(262144 / 2 + 8);
    unsigned short* W3_16 = (unsigned short*)alloc(262144 / 2 + 8);

    unsigned short* fa_in_w16  = w16;                       // 196608
    unsigned short* fa_out_w16 = fa_in_w16 + 196608;        // 65536
    unsigned short* mdw16      = fa_out_w16 + 65536;        // 32768
    unsigned short* l1w16      = mdw16 + 32768;             // 262144
    unsigned short* l2w16      = l1w16 + 262144;            // 262144  (ends 819200)

    unsigned short* qkv16 = (unsigned short*)bigA;
    unsigned short* G16 = (unsigned short*)bigA;
    float* x2  = bigA;
    unsigned short* Mo16 = (unsigned short*)Mh;
    unsigned short* h116 = (unsigned short*)Mh;
    unsigned short* cb16 = (unsigned short*)cbws;
    unsigned short* src16  = actBF1;
    unsigned short* abuf16 = actBF1;
    unsigned short* stb16  = actBF1;
    unsigned short* x216   = actBF2;

    // 0. convert weights + src to bf16; build absorbed W2/W3
    ConvArgs ca;
    const float* segs[8] = {src, fa_in_w, fa_out_w, mdw, l1w, l2w, iqw, ikw};
    unsigned short* segd[8] = {src16, fa_in_w16, fa_out_w16, mdw16, l1w16, l2w16,
                               wqk16, wqk16 + 8192};
    int segn[8] = {NT * E_, 196608, 65536, 32768, 262144, 262144, 8192, 8192};
    int cum = 0;
    for (int i = 0; i < 8; i++) { ca.s[i] = segs[i]; ca.d[i] = segd[i]; cum += segn[i] / 4; ca.cum[i] = cum; }
    int totq = cum;
    convert_f2b<<<(totq + 255) / 256, 256, 0, stream>>>(ca, totq);
    make_w2w3<<<1280, 256, 0, stream>>>(mqw, muw, mow, W2_16, W3_16);

    dim3 blk(256);
    // 1. qkv16 = src @ fa_in_w^T + b  (bf16 out)
    gemm_mfma<128,128,1,0,0,0,0,1><<<dim3(6,64), blk, 0, stream>>>(src16, fa_in_w16, fa_in_b, nullptr, nullptr, qkv16, NT, 768, 256);
    // 2. feature attention (S=4) -> bf16
    fa_attn<<<2048, blk, 0, stream>>>(qkv16, abuf16);
    // 3. out-proj + bias + residual(src)
    gemm_mfma<128,64,1,0,1,0,0,0><<<dim3(4,64), blk, 0, stream>>>(abuf16, fa_out_w16, fa_out_b, src, tbuf, nullptr, NT, 256, 256);
    // 4. LN1, write transposed f32 + bf16
    ln_k<1,1><<<NT/4, blk, 0, stream>>>(tbuf, n1g, n1b, stb, stb16);
    // 5. indexer projections as MFMA GEMM -> qk32 [row][64]
    gemm_mfma<128,64,0,0,0,0,0,0><<<dim3(1,64), blk, 0, stream>>>(stb16, wqk16, nullptr, nullptr, qk32, nullptr, NT, 64, 256);
    // 6. scales + k-quant fused
    idx_scales_quant<<<96, blk, 0, stream>>>(qk32, scl, ki8);
    // 7. scores + top-32 (radix-select)
    idx_score_topk<<<NT, blk, 0, stream>>>(qk32, ki8, scl, iow, idxb);
    // 8. c = x_tr @ down_w^T  -> bf16 cb16
    gemm_mfma<64,64,0,0,0,1,0,1><<<dim3(2,96), blk, 0, stream>>>(stb16, mdw16, nullptr, nullptr, nullptr, cb16, BF * SPLIT, 128, 256);
    // 9. G16 = stb16 @ W2^T  (absorbed q-proj + up_K)
    gemm_mfma<128,128,0,0,0,0,0,1><<<dim3(8,64), blk, 0, stream>>>(stb16, W2_16, nullptr, nullptr, nullptr, G16, NT, 1024, 256);
    // 10. fused sparse attention (1 wave/query, 4/block) -> Mo16
    mla_attn<<<NT/4, blk, 0, stream>>>(G16, cb16, idxb, Mo16);
    // 11. tbuf = Mo16 @ W3^T + stb  (absorbed up_V + out-proj), scatter to BRCE
    gemm_mfma<128,128,0,0,1,0,1,0><<<dim3(2,64), blk, 0, stream>>>(Mo16, W3_16, nullptr, stb, tbuf, nullptr, NT, 256, 1024);
    // 12. LN2 -> x2 f32 + bf16
    ln_k<0,1><<<NT/4, blk, 0, stream>>>(tbuf, n2g, n2b, x2, x216);
    // 13. MLP1 + GELU -> bf16 h1
    gemm_mfma<128,128,1,1,0,0,0,1><<<dim3(8,64), blk, 0, stream>>>(x216, l1w16, l1b, nullptr, nullptr, h116, NT, MLPD, 256);
    // 14. MLP2 + bias + residual(x2)
    gemm_mfma<128,64,1,0,1,0,0,0><<<dim3(4,64), blk, 0, stream>>>(h116, l2w16, l2b, x2, tbuf, nullptr, NT, 256, MLPD);
    // 15. LN3 -> output
    ln_k<0,0><<<NT/4, blk, 0, stream>>>(tbuf, n3g, n3b, (float*)d_out, nullptr);
}

// Round 12
// 299.942 us; speedup vs baseline: 1.0644x; 1.0644x over previous
//
#include <hip/hip_runtime.h>
#include <hip/hip_bf16.h>
#include <cmath>

#define E_ 256
#define H_ 8
#define DH 32
#define MLPD 1024
#define LATD 128
#define TOPK_ 32
#define BB 2
#define RR 1024
#define CC 4
#define NT 8192      // B*R*C tokens
#define BF 8         // B*C
#define SPLIT 768

using bf16x8 = __attribute__((ext_vector_type(8))) short;
using f32x4v = __attribute__((ext_vector_type(4))) float;

__device__ __forceinline__ unsigned short f2b(float x) {
    __hip_bfloat16 h = __float2bfloat16(x);
    return *reinterpret_cast<unsigned short*>(&h);
}
__device__ __forceinline__ float b2f(unsigned short u) {
    return __uint_as_float(((unsigned)u) << 16);
}

// ---------------------------------------------------------------------------
// Fused f32 -> bf16 converter (8 segments)
// ---------------------------------------------------------------------------
struct ConvArgs {
    const float* s[8];
    unsigned short* d[8];
    int cum[8];
};
__global__ __launch_bounds__(256) void convert_f2b(ConvArgs a, int totq)
{
    int q = blockIdx.x * 256 + threadIdx.x;
    if (q >= totq) return;
    int seg = 0;
    while (q >= a.cum[seg]) seg++;
    int lq = q - (seg ? a.cum[seg - 1] : 0);
    float4 v = ((const float4*)a.s[seg])[lq];
    ushort4 o;
    o.x = f2b(v.x); o.y = f2b(v.y); o.z = f2b(v.z); o.w = f2b(v.w);
    ((ushort4*)a.d[seg])[lq] = o;
}

// ---------------------------------------------------------------------------
// Absorbed MLA weights (W2 written at rows 64.. of Wcomb by caller offset):
//   W2[hl][e] = sum_d muw[(h*32+d)][l] * mqw[(h*32+d)][e]        (K-half)
//   W3[e][hl] = sum_d mow[e][h*32+d]   * muw[256+h*32+d][l]      (V-half)
// ---------------------------------------------------------------------------
__global__ __launch_bounds__(256) void make_w2w3(const float* __restrict__ mqw,
                                                 const float* __restrict__ muw,
                                                 const float* __restrict__ mow,
                                                 unsigned short* __restrict__ W2,
                                                 unsigned short* __restrict__ W3)
{
    int b = blockIdx.x, t = threadIdx.x;
    if (b < 1024) {
        int h = b >> 7, l = b & 127;
        float s2 = 0;
#pragma unroll 8
        for (int d = 0; d < 32; d++)
            s2 += muw[(size_t)(h * 32 + d) * 128 + l] * mqw[(size_t)(h * 32 + d) * 256 + t];
        W2[(size_t)b * 256 + t] = f2b(s2);
    } else {
        int e = b - 1024;
        for (int tt = t; tt < 1024; tt += 256) {
            int h = tt >> 7, l = tt & 127;
            float s3 = 0;
#pragma unroll 8
            for (int d = 0; d < 32; d++)
                s3 += muw[(size_t)(256 + h * 32 + d) * 128 + l] * mow[(size_t)e * 256 + h * 32 + d];
            W3[(size_t)e * 1024 + tt] = f2b(s3);
        }
    }
}

// ---------------------------------------------------------------------------
// bf16 MFMA GEMM: C[M][N] = A(MxK bf16) @ W(NxK bf16)^T (+bias)(+gelu)(+res f32)
// OUTBF: 0 = f32 out (Cf, stride N); 1 = bf16 out (Ch, stride N);
//        2 = SPLIT: col<64 -> Cf f32 stride 64; col>=64 -> Ch bf16 stride 1024.
// ---------------------------------------------------------------------------
template<int TM, int TN, int BIAS, int GELU, int RES, int AMAP, int OMAP, int OUTBF>
__global__ __launch_bounds__(256) void gemm_mfma(
    const unsigned short* __restrict__ A, const unsigned short* __restrict__ W,
    const float* __restrict__ bias, const float* __restrict__ res,
    float* __restrict__ Cf, unsigned short* __restrict__ Ch,
    int M, int N, int K)
{
    __shared__ __align__(16) unsigned short As[TM * 40];
    __shared__ __align__(16) unsigned short Bs[TN * 40];
    const int tid = threadIdx.x;
    const int lane = tid & 63, wave = tid >> 6;
    const int wr = wave >> 1, wc = wave & 1;
    const int m0 = blockIdx.y * TM, n0 = blockIdx.x * TN;

    int ra, kqa;
    if constexpr (TM == 128) { ra = tid >> 1; kqa = (tid & 1) * 16; }
    else                     { ra = tid >> 2; kqa = (tid & 3) * 8; }
    int rb, kqb;
    if constexpr (TN == 128) { rb = tid >> 1; kqb = (tid & 1) * 16; }
    else                     { rb = tid >> 2; kqb = (tid & 3) * 8; }

    int am = m0 + ra;
    size_t arow = AMAP ? ((size_t)(am / SPLIT) * RR + (am % SPLIT)) : (size_t)am;
    const unsigned short* Ap = A + arow * (size_t)K + kqa;
    const unsigned short* Bp = W + (size_t)(n0 + rb) * K + kqb;

    constexpr int FM = TM / 32, FN = TN / 32;
    f32x4v acc[FM][FN];
#pragma unroll
    for (int i = 0; i < FM; i++)
#pragma unroll
        for (int j = 0; j < FN; j++) acc[i][j] = (f32x4v){0.f, 0.f, 0.f, 0.f};

    const int kof = (lane >> 4) * 8;
    int arow_lds[FM], brow_lds[FN];
#pragma unroll
    for (int f = 0; f < FM; f++)
        arow_lds[f] = (wr * (TM / 2) + f * 16 + (lane & 15)) * 40 + kof;
#pragma unroll
    for (int f = 0; f < FN; f++)
        brow_lds[f] = (wc * (TN / 2) + f * 16 + (lane & 15)) * 40 + kof;

    for (int k0 = 0; k0 < K; k0 += 32) {
        int4 va0, va1, vb0, vb1;
        va0 = *(const int4*)(Ap + k0);
        if constexpr (TM == 128) va1 = *(const int4*)(Ap + k0 + 8);
        vb0 = *(const int4*)(Bp + k0);
        if constexpr (TN == 128) vb1 = *(const int4*)(Bp + k0 + 8);
        __syncthreads();
        *(int4*)&As[ra * 40 + kqa] = va0;
        if constexpr (TM == 128) *(int4*)&As[ra * 40 + kqa + 8] = va1;
        *(int4*)&Bs[rb * 40 + kqb] = vb0;
        if constexpr (TN == 128) *(int4*)&Bs[rb * 40 + kqb + 8] = vb1;
        __syncthreads();
        bf16x8 af[FM], bfr[FN];
#pragma unroll
        for (int f = 0; f < FM; f++) af[f] = *(const bf16x8*)&As[arow_lds[f]];
#pragma unroll
        for (int f = 0; f < FN; f++) bfr[f] = *(const bf16x8*)&Bs[brow_lds[f]];
#pragma unroll
        for (int fm = 0; fm < FM; fm++)
#pragma unroll
            for (int fn = 0; fn < FN; fn++)
                acc[fm][fn] = __builtin_amdgcn_mfma_f32_16x16x32_bf16(
                    af[fm], bfr[fn], acc[fm][fn], 0, 0, 0);
    }

#pragma unroll
    for (int fm = 0; fm < FM; fm++) {
#pragma unroll
        for (int r = 0; r < 4; r++) {
            int row = m0 + wr * (TM / 2) + fm * 16 + ((lane >> 4) << 2) + r;
            size_t orow;
            if (OMAP) {
                int bc = row >> 10, rr = row & 1023;
                int b = bc >> 2, c = bc & 3;
                orow = ((size_t)(b * RR + rr)) * CC + c;
            } else orow = (size_t)row;
#pragma unroll
            for (int fn = 0; fn < FN; fn++) {
                int col = n0 + wc * (TN / 2) + fn * 16 + (lane & 15);
                float v = acc[fm][fn][r];
                if (BIAS) v += bias[col];
                if (GELU) v = 0.5f * v * (1.0f + erff(v * 0.70710678118654752f));
                if (RES)  v += res[(size_t)row * N + col];
                if constexpr (OUTBF == 2) {
                    if (col < 64) Cf[orow * 64 + col] = v;
                    else          Ch[orow * 1024 + (col - 64)] = f2b(v);
                } else if constexpr (OUTBF == 1) {
                    Ch[orow * (size_t)N + col] = f2b(v);
                } else {
                    Cf[orow * (size_t)N + col] = v;
                }
            }
        }
    }
}

// ---------------------------------------------------------------------------
// Feature attention: seq len 4, per (b,r) block. Reads bf16 qkv.
// ---------------------------------------------------------------------------
__global__ __launch_bounds__(256) void fa_attn(const unsigned short* __restrict__ qkv16,
                                               unsigned short* __restrict__ outb)
{
    int seq = blockIdx.x, tid = threadIdx.x;
    __shared__ float sq[4][E_], sk[4][E_], sv[4][E_];
    __shared__ float ss[H_][4][4];
    __shared__ float sw[H_][4][4];
    const uint4* base = (const uint4*)(qkv16 + (size_t)seq * 3072);
#pragma unroll
    for (int p = 0; p < 2; p++) {
        int pos = tid + p * 256;           // 0..383 uint4 units (8 bf16 each)
        if (pos < 384) {
            uint4 v = base[pos];
            unsigned short u[8];
            *(uint4*)u = v;
            int flat = pos * 8;
            int i = flat / 768, c = flat % 768;
            float* dst = (c < 256) ? &sq[i][c] : (c < 512) ? &sk[i][c - 256] : &sv[i][c - 512];
#pragma unroll
            for (int t = 0; t < 8; t++) dst[t] = b2f(u[t]);
        }
    }
    __syncthreads();
    if (tid < 128) {
        int h = tid >> 4, i = (tid >> 2) & 3, j = tid & 3;
        float s = 0;
        for (int d = 0; d < DH; d++) s += sq[i][h * DH + d] * sk[j][h * DH + d];
        ss[h][i][j] = s * 0.17677669529663688f;   // 1/sqrt(32)
    }
    __syncthreads();
    if (tid < 32) {
        int h = tid >> 2, i = tid & 3;
        float m = ss[h][i][0];
        for (int j = 1; j < 4; j++) m = fmaxf(m, ss[h][i][j]);
        float e[4], sum = 0;
        for (int j = 0; j < 4; j++) { e[j] = expf(ss[h][i][j] - m); sum += e[j]; }
        float inv = 1.0f / sum;
        for (int j = 0; j < 4; j++) sw[h][i][j] = e[j] * inv;
    }
    __syncthreads();
    int e = tid, h = e >> 5;
    for (int i = 0; i < 4; i++) {
        float o = 0;
        for (int j = 0; j < 4; j++) o += sw[h][i][j] * sv[j][e];
        outb[((size_t)(seq * 4 + i)) * E_ + e] = f2b(o);
    }
}

// ---------------------------------------------------------------------------
// LayerNorm: 4 rows per block (one row per wave). OMAP=1: token -> st row.
// ---------------------------------------------------------------------------
template<int OMAP, int WB>
__global__ __launch_bounds__(256) void ln_k(const float* __restrict__ in,
                                            const float* __restrict__ g,
                                            const float* __restrict__ bta,
                                            float* __restrict__ out,
                                            unsigned short* __restrict__ outh)
{
    int row = blockIdx.x * 4 + (threadIdx.x >> 6);
    int t = threadIdx.x & 63;
    float4 v = ((const float4*)(in + (size_t)row * E_))[t];
    float s = v.x + v.y + v.z + v.w;
#pragma unroll
    for (int o = 32; o >= 1; o >>= 1) s += __shfl_xor(s, o);
    float mean = s * (1.0f / E_);
    float dx0 = v.x - mean, dx1 = v.y - mean, dx2 = v.z - mean, dx3 = v.w - mean;
    float q = dx0 * dx0 + dx1 * dx1 + dx2 * dx2 + dx3 * dx3;
#pragma unroll
    for (int o = 32; o >= 1; o >>= 1) q += __shfl_xor(q, o);
    float inv = rsqrtf(q * (1.0f / E_) + 1e-5f);
    size_t orow;
    if (OMAP == 1) {
        int b = row >> 12, r = (row >> 2) & 1023, c = row & 3;
        orow = ((size_t)(b * CC + c)) * RR + r;
    } else orow = (size_t)row;
    int c0 = t * 4;
    float4 o;
    o.x = dx0 * inv * g[c0 + 0] + bta[c0 + 0];
    o.y = dx1 * inv * g[c0 + 1] + bta[c0 + 1];
    o.z = dx2 * inv * g[c0 + 2] + bta[c0 + 2];
    o.w = dx3 * inv * g[c0 + 3] + bta[c0 + 3];
    ((float4*)(out + orow * E_))[t] = o;
    if (WB) {
        ushort4 oh; oh.x = f2b(o.x); oh.y = f2b(o.y); oh.z = f2b(o.z); oh.w = f2b(o.w);
        ((ushort4*)(outh + orow * E_))[t] = oh;
    }
}

// ---------------------------------------------------------------------------
// Indexer scales + k-quantize fused.
// ---------------------------------------------------------------------------
__global__ __launch_bounds__(256) void idx_scales_quant(const float* __restrict__ qk32,
                                                        float* __restrict__ scl,
                                                        signed char* __restrict__ ki8)
{
    int id = blockIdx.x;
    int type = id / 32, bf = (id % 32) >> 2, h = id & 3;
    int cofs = (type == 2) ? 32 : 0;
    int r0 = (type == 1) ? SPLIT : 0;
    int r1 = (type == 1) ? RR : SPLIT;
    float m = 0;
    for (int r = r0 + (int)threadIdx.x; r < r1; r += 256) {
        const float* p = qk32 + ((size_t)(bf * RR + r)) * 64 + cofs + h * 8;
        for (int dd = 0; dd < 8; dd++) m = fmaxf(m, fabsf(p[dd]));
    }
#pragma unroll
    for (int o = 32; o >= 1; o >>= 1) m = fmaxf(m, __shfl_xor(m, o));
    __shared__ float red[4];
    __shared__ float sscl;
    if ((threadIdx.x & 63) == 0) red[threadIdx.x >> 6] = m;
    __syncthreads();
    if (threadIdx.x == 0) {
        m = fmaxf(fmaxf(red[0], red[1]), fmaxf(red[2], red[3]));
        float sc = (m + 1e-6f) / 127.0f;
        scl[id] = sc;
        sscl = sc;
    }
    __syncthreads();
    if (type == 2) {
        float ks = sscl;
        for (int r = threadIdx.x; r < SPLIT; r += 256) {
            const float* p = qk32 + ((size_t)(bf * RR + r)) * 64 + 32 + h * 8;
            signed char* o = ki8 + ((size_t)(bf * SPLIT + r)) * 32 + h * 8;
#pragma unroll
            for (int dd = 0; dd < 8; dd++)
                o[dd] = (signed char)fminf(fmaxf(rintf(p[dd] / ks), -127.f), 127.f);
        }
    }
}

// ---------------------------------------------------------------------------
// Indexer scores + top-32 via EXACT radix-select (jax.lax.top_k tie rule).
// Fast path: if level-1 threshold bucket is thin (S1+hist[b1] <= 160), skip
// the level-2 histogram (exact: larger candidate superset, same rank-count).
// ---------------------------------------------------------------------------
__global__ __launch_bounds__(256) void idx_score_topk(const float* __restrict__ qk32,
                                                      const signed char* __restrict__ ki8,
                                                      const float* __restrict__ scl,
                                                      const float* __restrict__ ow,
                                                      int* __restrict__ idx_out)
{
    int bid = blockIdx.x, tid = threadIdx.x;
    int bf = bid >> 10, qr = bid & 1023;
    int sel = (qr < SPLIT) ? 0 : 32;
    __shared__ float qi[32];
    __shared__ float fac[4];
    __shared__ unsigned keyhi[SPLIT];
    __shared__ __align__(16) unsigned long long cand[SPLIT];
    __shared__ int hist[256], hist2[256], Sarr[256];
    __shared__ int bsel1, bsel2, ccnt;

    hist[tid] = 0; hist2[tid] = 0;
    if (tid == 0) ccnt = 0;
    if (tid < 32) {
        int h = tid >> 3;
        float qs = scl[sel + bf * 4 + h];
        float v = qk32[(size_t)bid * 64 + tid];
        qi[tid] = fminf(fmaxf(rintf(v / qs), -127.f), 127.f);
    }
    if (tid < 4) {
        float qs = scl[sel + bf * 4 + tid];
        float ks = scl[64 + bf * 4 + tid];
        fac[tid] = __fmul_rn(qs, ks);
    }
    __syncthreads();
    float ow0 = ow[0], ow1 = ow[1], ow2 = ow[2], ow3 = ow[3];
    for (int k = tid; k < SPLIT; k += 256) {
        const int4* kp4 = (const int4*)(ki8 + ((size_t)(bf * SPLIT + k)) * 32);
        int4 w0 = kp4[0], w1 = kp4[1];
        int wd[8] = {w0.x, w0.y, w0.z, w0.w, w1.x, w1.y, w1.z, w1.w};
        float owv[4] = {ow0, ow1, ow2, ow3};
        float r = 0;
#pragma unroll
        for (int h = 0; h < 4; h++) {
            float dot = 0.f;
#pragma unroll
            for (int b = 0; b < 2; b++) {
                unsigned int w = (unsigned int)wd[h * 2 + b];
#pragma unroll
                for (int by = 0; by < 4; by++) {
                    float kv = (float)((signed char)(w >> (8 * by)));
                    dot = fmaf(qi[h * 8 + b * 4 + by], kv, dot);
                }
            }
            float sc = fmaxf(__fmul_rn(dot, fac[h]), 0.f);
            r = __fadd_rn(r, __fmul_rn(sc, owv[h]));
        }
        unsigned int bitsv = __float_as_uint(r);
        unsigned int mono = (bitsv & 0x80000000u) ? ~bitsv : (bitsv | 0x80000000u);
        if (mono == 0x7FFFFFFFu) mono = 0x80000000u;   // canonicalize -0 == +0
        keyhi[k] = mono;
        atomicAdd(&hist[mono >> 24], 1);
    }
    __syncthreads();
    if (tid < 64) {
        int4 h4 = *(const int4*)&hist[tid * 4];
        int local = h4.x + h4.y + h4.z + h4.w;
        int s = local;
#pragma unroll
        for (int o = 1; o < 64; o <<= 1) {
            int x = __shfl_down(s, o);
            if (tid + o < 64) s += x;
        }
        int sufE = s - local;
        Sarr[tid * 4 + 0] = sufE + h4.y + h4.z + h4.w;
        Sarr[tid * 4 + 1] = sufE + h4.z + h4.w;
        Sarr[tid * 4 + 2] = sufE + h4.w;
        Sarr[tid * 4 + 3] = sufE;
    }
    __syncthreads();
    if (Sarr[tid] < TOPK_ && Sarr[tid] + hist[tid] >= TOPK_) bsel1 = tid;
    __syncthreads();
    const int b1 = bsel1;
    const int S1 = Sarr[b1];
    const bool fast = (S1 + hist[b1] <= 160);
    int b2 = 0;
    if (!fast) {
        for (int k = tid; k < SPLIT; k += 256) {
            unsigned mono = keyhi[k];
            if ((int)(mono >> 24) == b1) atomicAdd(&hist2[(mono >> 16) & 255], 1);
        }
        __syncthreads();
        if (tid < 64) {
            int4 h4 = *(const int4*)&hist2[tid * 4];
            int local = h4.x + h4.y + h4.z + h4.w;
            int s = local;
#pragma unroll
            for (int o = 1; o < 64; o <<= 1) {
                int x = __shfl_down(s, o);
                if (tid + o < 64) s += x;
            }
            int sufE = s - local;
            Sarr[tid * 4 + 0] = sufE + h4.y + h4.z + h4.w;
            Sarr[tid * 4 + 1] = sufE + h4.z + h4.w;
            Sarr[tid * 4 + 2] = sufE + h4.w;
            Sarr[tid * 4 + 3] = sufE;
        }
        __syncthreads();
        if (S1 + Sarr[tid] < TOPK_ && S1 + Sarr[tid] + hist2[tid] >= TOPK_) bsel2 = tid;
        __syncthreads();
        b2 = bsel2;
    }
    for (int k = tid; k < SPLIT; k += 256) {
        unsigned mono = keyhi[k];
        int hi = mono >> 24, mid = (mono >> 16) & 255;
        if (hi > b1 || (hi == b1 && mid >= b2)) {
            int s = atomicAdd(&ccnt, 1);
            cand[s] = ((unsigned long long)mono << 10) | (unsigned)(1023 - k);
        }
    }
    __syncthreads();
    const int n = ccnt;
    for (int ci = tid; ci < n; ci += 256) {
        unsigned long long mine = cand[ci];
        int r = 0;
        for (int j = 0; j < n; j++) r += (cand[j] > mine);
        if (r < TOPK_)
            idx_out[(size_t)bid * TOPK_ + r] = 1023 - (int)(mine & 1023ull);
    }
}

// ---------------------------------------------------------------------------
// Fused sparse MLA attention: one wave per query, 4 queries per block.
// Barrier-free (each wave owns a disjoint LDS slice).
// ---------------------------------------------------------------------------
__global__ __launch_bounds__(256) void mla_attn(const unsigned short* __restrict__ G16,
                                                const unsigned short* __restrict__ cb16,
                                                const int* __restrict__ idxb,
                                                unsigned short* __restrict__ Mo16)
{
    const int w = threadIdx.x >> 6, l = threadIdx.x & 63;
    const int bid = blockIdx.x * 4 + w;
    const int bf = bid >> 10;
    __shared__ __align__(16) unsigned short ct[4][128][40];  // C^T per wave
    __shared__ __align__(16) unsigned short wT[4][16][40];   // w^T per wave
    __shared__ int sidx[4][32];
    if (l < 32) sidx[w][l] = idxb[(size_t)bid * 32 + l];

    const int n16 = l & 15, g = l >> 4;

    // ---- stage C^T (transpose write) ----
    {
        int j = l >> 1, c0 = (l & 1) * 64;
        const unsigned short* crow = cb16 + ((size_t)(bf * SPLIT + sidx[w][j])) * 128 + c0;
#pragma unroll
        for (int e = 0; e < 8; e++) {
            uint4 v = *(const uint4*)(crow + e * 8);
            unsigned short tmp[8];
            *(uint4*)tmp = v;
#pragma unroll
            for (int t = 0; t < 8; t++) ct[w][c0 + e * 8 + t][j] = tmp[t];
        }
    }

    // ---- scores: S^T = G @ C^T (global-direct fragments) ----
    const unsigned short* Ab = G16 + (size_t)bid * 1024 + (size_t)(l & 7) * 128 + g * 8;
    const int j0 = sidx[w][n16], j1 = sidx[w][16 + n16];
    const unsigned short* B0 = cb16 + ((size_t)(bf * SPLIT + j0)) * 128 + g * 8;
    const unsigned short* B1 = cb16 + ((size_t)(bf * SPLIT + j1)) * 128 + g * 8;
    f32x4v s0 = {0.f, 0.f, 0.f, 0.f}, s1 = {0.f, 0.f, 0.f, 0.f};
#pragma unroll
    for (int c = 0; c < 4; c++) {
        bf16x8 a  = *(const bf16x8*)(Ab + c * 32);
        bf16x8 b0 = *(const bf16x8*)(B0 + c * 32);
        bf16x8 b1 = *(const bf16x8*)(B1 + c * 32);
        s0 = __builtin_amdgcn_mfma_f32_16x16x32_bf16(a, b0, s0, 0, 0, 0);
        s1 = __builtin_amdgcn_mfma_f32_16x16x32_bf16(a, b1, s1, 0, 0, 0);
    }

    // ---- softmax over j (32 vals: 16 lanes x 2 regs), per h-row ----
    const float scale = 0.17677669529663688f;
#pragma unroll
    for (int r = 0; r < 4; r++) {
        float a0 = s0[r] * scale, a1 = s1[r] * scale;
        float mx = fmaxf(a0, a1);
#pragma unroll
        for (int o = 1; o < 16; o <<= 1) mx = fmaxf(mx, __shfl_xor(mx, o));
        float e0 = expf(a0 - mx), e1 = expf(a1 - mx);
        float sm = e0 + e1;
#pragma unroll
        for (int o = 1; o < 16; o <<= 1) sm += __shfl_xor(sm, o);
        float inv = 1.0f / sm;
        wT[w][g * 4 + r][n16]      = f2b(e0 * inv);
        wT[w][g * 4 + r][16 + n16] = f2b(e1 * inv);
    }

    // ---- PV: M = W^T @ C ----
    bf16x8 aw = *(const bf16x8*)&wT[w][n16][g * 8];
#pragma unroll
    for (int t = 0; t < 8; t++) {
        bf16x8 bc = *(const bf16x8*)&ct[w][t * 16 + n16][g * 8];
        f32x4v m = {0.f, 0.f, 0.f, 0.f};
        m = __builtin_amdgcn_mfma_f32_16x16x32_bf16(aw, bc, m, 0, 0, 0);
        if (g < 2) {
#pragma unroll
            for (int r = 0; r < 4; r++)
                Mo16[(size_t)bid * 1024 + (size_t)(g * 4 + r) * 128 + t * 16 + n16] = f2b(m[r]);
        }
    }
}

// ---------------------------------------------------------------------------
extern "C" void kernel_launch(void* const* d_in, const int* in_sizes, int n_in,
                              void* d_out, int out_size, void* d_ws, size_t ws_size,
                              hipStream_t stream)
{
    (void)in_sizes; (void)n_in; (void)out_size; (void)ws_size;
    const float* src      = (const float*)d_in[0];
    const float* fa_in_w  = (const float*)d_in[2];
    const float* fa_in_b  = (const float*)d_in[3];
    const float* fa_out_w = (const float*)d_in[4];
    const float* fa_out_b = (const float*)d_in[5];
    const float* n1g = (const float*)d_in[6];
    const float* n1b = (const float*)d_in[7];
    const float* iqw = (const float*)d_in[8];
    const float* ikw = (const float*)d_in[9];
    const float* iow = (const float*)d_in[10];
    const float* mqw = (const float*)d_in[11];
    const float* mdw = (const float*)d_in[12];
    const float* muw = (const float*)d_in[13];
    const float* mow = (const float*)d_in[14];
    const float* n2g = (const float*)d_in[15];
    const float* n2b = (const float*)d_in[16];
    const float* l1w = (const float*)d_in[17];
    const float* l1b = (const float*)d_in[18];
    const float* l2w = (const float*)d_in[19];
    const float* l2b = (const float*)d_in[20];
    const float* n3g = (const float*)d_in[21];
    const float* n3b = (const float*)d_in[22];

    float* ws = (float*)d_ws;
    size_t off = 0;
    auto alloc = [&](size_t n) { float* p = ws + off; off += (n + 3) & ~(size_t)3; return p; };

    float* bigA = alloc((size_t)NT * 1024);   // qkv16 -> G16 -> x2
    float* Mh   = alloc((size_t)NT * 1024);   // Mo16; later h1 bf16
    float* tbuf = alloc((size_t)NT * E_);     // pre-LN buffer
    float* stb  = alloc((size_t)NT * E_);     // st f32 (post-LN1, transposed)
    float* cbws = alloc((size_t)BF * SPLIT * LATD / 2 + 16);   // cb16 bf16
    unsigned short* actBF1 = (unsigned short*)alloc((size_t)NT * E_ / 2);
    unsigned short* actBF2 = (unsigned short*)alloc((size_t)NT * E_ / 2);
    float* qk32 = alloc((size_t)NT * 64);
    float* scl = alloc(128);
    int*   idxb = (int*)alloc((size_t)NT * 32);
    signed char* ki8 = (signed char*)alloc((size_t)NT * 32 / 4);
    // w16: 5 segments summing to 819200 bf16 (see layout below)
    unsigned short* w16 = (unsigned short*)alloc(819200 / 2 + 16);
    // Wcomb: rows 0-63 = [iqw;ikw], rows 64-1087 = W2  (1088 x 256 bf16)
    unsigned short* Wcomb = (unsigned short*)alloc(278528 / 2 + 16);
    unsigned short* W3_16 = (unsigned short*)alloc(262144 / 2 + 8);

    unsigned short* fa_in_w16  = w16;                       // 196608
    unsigned short* fa_out_w16 = fa_in_w16 + 196608;        // 65536
    unsigned short* mdw16      = fa_out_w16 + 65536;        // 32768
    unsigned short* l1w16      = mdw16 + 32768;             // 262144
    unsigned short* l2w16      = l1w16 + 262144;            // 262144  (ends 819200)

    unsigned short* wqk16 = Wcomb;                          // rows 0-63
    unsigned short* W2_16 = Wcomb + 64 * 256;               // rows 64-1087

    unsigned short* qkv16 = (unsigned short*)bigA;
    unsigned short* G16 = (unsigned short*)bigA;
    float* x2  = bigA;
    unsigned short* Mo16 = (unsigned short*)Mh;
    unsigned short* h116 = (unsigned short*)Mh;
    unsigned short* cb16 = (unsigned short*)cbws;
    unsigned short* src16  = actBF1;
    unsigned short* abuf16 = actBF1;
    unsigned short* stb16  = actBF1;
    unsigned short* x216   = actBF2;

    // 0. convert weights + src to bf16; build absorbed W2/W3
    ConvArgs ca;
    const float* segs[8] = {src, fa_in_w, fa_out_w, mdw, l1w, l2w, iqw, ikw};
    unsigned short* segd[8] = {src16, fa_in_w16, fa_out_w16, mdw16, l1w16, l2w16,
                               wqk16, wqk16 + 8192};
    int segn[8] = {NT * E_, 196608, 65536, 32768, 262144, 262144, 8192, 8192};
    int cum = 0;
    for (int i = 0; i < 8; i++) { ca.s[i] = segs[i]; ca.d[i] = segd[i]; cum += segn[i] / 4; ca.cum[i] = cum; }
    int totq = cum;
    convert_f2b<<<(totq + 255) / 256, 256, 0, stream>>>(ca, totq);
    make_w2w3<<<1280, 256, 0, stream>>>(mqw, muw, mow, W2_16, W3_16);

    dim3 blk(256);
    // 1. qkv16 = src @ fa_in_w^T + b  (bf16 out)
    gemm_mfma<128,128,1,0,0,0,0,1><<<dim3(6,64), blk, 0, stream>>>(src16, fa_in_w16, fa_in_b, nullptr, nullptr, qkv16, NT, 768, 256);
    // 2. feature attention (S=4) -> bf16
    fa_attn<<<2048, blk, 0, stream>>>(qkv16, abuf16);
    // 3. out-proj + bias + residual(src)
    gemm_mfma<128,64,1,0,1,0,0,0><<<dim3(4,64), blk, 0, stream>>>(abuf16, fa_out_w16, fa_out_b, src, tbuf, nullptr, NT, 256, 256);
    // 4. LN1, write transposed f32 + bf16
    ln_k<1,1><<<NT/4, blk, 0, stream>>>(tbuf, n1g, n1b, stb, stb16);
    // 5+9. fused indexer-proj + absorbed G: [qk32 | G16] = stb16 @ Wcomb^T
    gemm_mfma<128,64,0,0,0,0,0,2><<<dim3(17,64), blk, 0, stream>>>(stb16, Wcomb, nullptr, nullptr, qk32, G16, NT, 1088, 256);
    // 6. scales + k-quant fused
    idx_scales_quant<<<96, blk, 0, stream>>>(qk32, scl, ki8);
    // 7. scores + top-32 (radix-select + fast path)
    idx_score_topk<<<NT, blk, 0, stream>>>(qk32, ki8, scl, iow, idxb);
    // 8. c = x_tr @ down_w^T  -> bf16 cb16
    gemm_mfma<64,64,0,0,0,1,0,1><<<dim3(2,96), blk, 0, stream>>>(stb16, mdw16, nullptr, nullptr, nullptr, cb16, BF * SPLIT, 128, 256);
    // 10. fused sparse attention (1 wave/query, 4/block) -> Mo16
    mla_attn<<<NT/4, blk, 0, stream>>>(G16, cb16, idxb, Mo16);
    // 11. tbuf = Mo16 @ W3^T + stb  (absorbed up_V + out-proj), scatter to BRCE
    gemm_mfma<64,64,0,0,1,0,1,0><<<dim3(4,128), blk, 0, stream>>>(Mo16, W3_16, nullptr, stb, tbuf, nullptr, NT, 256, 1024);
    // 12. LN2 -> x2 f32 + bf16
    ln_k<0,1><<<NT/4, blk, 0, stream>>>(tbuf, n2g, n2b, x2, x216);
    // 13. MLP1 + GELU -> bf16 h1
    gemm_mfma<128,128,1,1,0,0,0,1><<<dim3(8,64), blk, 0, stream>>>(x216, l1w16, l1b, nullptr, nullptr, h116, NT, MLPD, 256);
    // 14. MLP2 + bias + residual(x2)
    gemm_mfma<64,64,1,0,1,0,0,0><<<dim3(4,128), blk, 0, stream>>>(h116, l2w16, l2b, x2, tbuf, nullptr, NT, 256, MLPD);
    // 15. LN3 -> output
    ln_k<0,0><<<NT/4, blk, 0, stream>>>(tbuf, n3g, n3b, (float*)d_out, nullptr);
}